// Round 4
// baseline (864.409 us; speedup 1.0000x reference)
//
#include <hip/hip_runtime.h>

#define BB 4
#define CC 128
#define NN 65536
#define HEADS 8
#define HD 16
#define TN 32
#define NTILES (NN / TN)   // 2048
#define TPB 256
#define K1_GRIDX 192       // blocks per batch for kernel1 (persistent, grid-stride)
#define QSTR 36            // padded LDS stride (16B aligned, breaks pow2 banks)

// NOTE: macro params must NOT be named w/x/y/z — token substitution would
// rewrite the .w member access (that was R0's compile failure).
#define RANK1(acc_, wgt_, xv_)                \
  (acc_)[0] = fmaf((wgt_), (xv_).x, (acc_)[0]); \
  (acc_)[1] = fmaf((wgt_), (xv_).y, (acc_)[1]); \
  (acc_)[2] = fmaf((wgt_), (xv_).z, (acc_)[2]); \
  (acc_)[3] = fmaf((wgt_), (xv_).w, (acc_)[3]);

// ---------------------------------------------------------------------------
// Kernel 1: ctx[b,h,i,j] = sum_n relu(Wk x + bk)[h*16+i, n] * (Wv x + bv)[h*16+j, n]
// ---------------------------------------------------------------------------
__global__ __launch_bounds__(TPB) void k1_context(
    const float* __restrict__ x,
    const float* __restrict__ Wk, const float* __restrict__ bk,
    const float* __restrict__ Wv, const float* __restrict__ bv,
    float* __restrict__ ctx)
{
  __shared__ float Xs[CC][TN];     // 16 KB (unpadded; b128 access conflict-free)
  __shared__ float Ks[CC][QSTR];   // 18 KB
  __shared__ float Vs[CC][QSTR];   // 18 KB   -> 52 KB total, 3 blocks/CU

  const int b  = blockIdx.y;
  const int t  = threadIdx.x;
  const int tc = t & 7, tr = t >> 3;     // proj mapping: 4 cols x 4 channels
  const int n0 = tc * 4, c0 = tr * 4;
  const int p  = t & 127, hf = t >> 7;   // stage-B mapping: (h,i) pair + column half
  const int h  = p >> 4, iq = p & 15;
  const int krow = h * HD + iq;

  float bK[4], bV[4];
#pragma unroll
  for (int cc = 0; cc < 4; ++cc) { bK[cc] = bk[c0 + cc]; bV[cc] = bv[c0 + cc]; }

  float ck[HD];
#pragma unroll
  for (int j = 0; j < HD; ++j) ck[j] = 0.f;

  const float* xb = x + (size_t)b * CC * NN;
  bool have = false;

  for (int tile = blockIdx.x; tile < NTILES; tile += K1_GRIDX) {
    const int nbase = tile * TN;

    // ---- load X tile (global -> LDS); overlaps with stage B of previous tile
    {
      const int g = t & 7, r0 = t >> 3;
#pragma unroll
      for (int k = 0; k < 4; ++k) {
        const int r = r0 + 32 * k;
        *(float4*)&Xs[r][g * 4] =
            *(const float4*)&xb[(size_t)r * NN + nbase + g * 4];
      }
    }

    // ---- stage B: context accumulation for PREVIOUS tile (reads Ks/Vs)
    if (have) {
#pragma unroll 4
      for (int cl = 0; cl < 16; ++cl) {
        const int col = hf * 16 + cl;
        const float kk = Ks[krow][col];
#pragma unroll
        for (int j = 0; j < HD; ++j) ck[j] = fmaf(kk, Vs[h * HD + j][col], ck[j]);
      }
    }
    __syncthreads();  // Xs ready; everyone done reading Ks/Vs

    // ---- K and V projections (read Xs, write Ks/Vs)
    {
      float aK[4][4], aV[4][4];
#pragma unroll
      for (int a = 0; a < 4; ++a)
#pragma unroll
        for (int j = 0; j < 4; ++j) { aK[a][j] = 0.f; aV[a][j] = 0.f; }

#pragma unroll 2
      for (int ci = 0; ci < CC; ci += 4) {
        const float4 x0 = *(const float4*)&Xs[ci + 0][n0];
        const float4 x1 = *(const float4*)&Xs[ci + 1][n0];
        const float4 x2 = *(const float4*)&Xs[ci + 2][n0];
        const float4 x3 = *(const float4*)&Xs[ci + 3][n0];
#pragma unroll
        for (int cc = 0; cc < 4; ++cc) {
          const float4 wk4 = *(const float4*)&Wk[(c0 + cc) * CC + ci];
          const float4 wv4 = *(const float4*)&Wv[(c0 + cc) * CC + ci];
          float* aK_ = aK[cc];
          float* aV_ = aV[cc];
          RANK1(aK_, wk4.x, x0); RANK1(aK_, wk4.y, x1);
          RANK1(aK_, wk4.z, x2); RANK1(aK_, wk4.w, x3);
          RANK1(aV_, wv4.x, x0); RANK1(aV_, wv4.y, x1);
          RANK1(aV_, wv4.z, x2); RANK1(aV_, wv4.w, x3);
        }
      }
#pragma unroll
      for (int cc = 0; cc < 4; ++cc) {
        float4 ko, vo;
        ko.x = fmaxf(aK[cc][0] + bK[cc], 0.f);
        ko.y = fmaxf(aK[cc][1] + bK[cc], 0.f);
        ko.z = fmaxf(aK[cc][2] + bK[cc], 0.f);
        ko.w = fmaxf(aK[cc][3] + bK[cc], 0.f);
        vo.x = aV[cc][0] + bV[cc];
        vo.y = aV[cc][1] + bV[cc];
        vo.z = aV[cc][2] + bV[cc];
        vo.w = aV[cc][3] + bV[cc];
        *(float4*)&Ks[c0 + cc][n0] = ko;
        *(float4*)&Vs[c0 + cc][n0] = vo;
      }
    }
    __syncthreads();  // Ks/Vs ready for stage B next iteration
    have = true;
  }

  // ---- stage B for the last tile
  if (have) {
#pragma unroll 4
    for (int cl = 0; cl < 16; ++cl) {
      const int col = hf * 16 + cl;
      const float kk = Ks[krow][col];
#pragma unroll
      for (int j = 0; j < HD; ++j) ck[j] = fmaf(kk, Vs[h * HD + j][col], ck[j]);
    }
  }
  __syncthreads();

  // ---- reduce the two column-halves via LDS scratch (reuse Xs), then atomicAdd
  if (hf == 1) {
#pragma unroll
    for (int j = 0; j < HD; ++j) Xs[p][j] = ck[j];
  }
  __syncthreads();
  if (hf == 0) {
    float* cdst = ctx + (size_t)b * HEADS * HD * HD + krow * HD;
#pragma unroll
    for (int j = 0; j < HD; ++j) atomicAdd(&cdst[j], ck[j] + Xs[p][j]);
  }
}

// ---------------------------------------------------------------------------
// Kernel 2: M[b][o][h*16+i] = sum_j Wr[o, h*16+j] * ctx[b,h,i,j]
// grid = (BB, 2): second dim splits the o-range to shorten the tail.
// ---------------------------------------------------------------------------
__global__ __launch_bounds__(TPB) void k2_fold(
    const float* __restrict__ Wr, const float* __restrict__ ctx,
    float* __restrict__ M)
{
  const int b = blockIdx.x;
  const int half = blockIdx.y;                  // o in [half*64, half*64+64)
  const float* cb = ctx + (size_t)b * HEADS * HD * HD;
  const int base = half * (CC / 2) * CC;        // 64*128 elements per half
  for (int k = threadIdx.x; k < (CC / 2) * CC; k += TPB) {
    const int idx = base + k;
    const int o = idx >> 7, c = idx & (CC - 1);
    const int h = c >> 4, i = c & 15;
    const float* cr = cb + h * HD * HD + i * HD;
    const float* wr = Wr + o * CC + h * HD;
    float s = 0.f;
#pragma unroll
    for (int j = 0; j < HD; ++j) s = fmaf(wr[j], cr[j], s);
    M[((size_t)b << 14) + idx] = s;
  }
}

// ---------------------------------------------------------------------------
// Kernel 3: out = M[b] @ relu(Wq x + bq) + br
// ---------------------------------------------------------------------------
__global__ __launch_bounds__(TPB) void k3_out(
    const float* __restrict__ x,
    const float* __restrict__ Wq, const float* __restrict__ bq,
    const float* __restrict__ M, const float* __restrict__ br,
    float* __restrict__ out)
{
  __shared__ float Xs[CC][TN];     // 16 KB
  __shared__ float Qs[CC][QSTR];   // 18 KB  -> 34 KB, 4 blocks/CU

  const int b = blockIdx.y;
  const int tile = blockIdx.x;
  const int t = threadIdx.x;
  const int tc = t & 7, tr = t >> 3;
  const int n0 = tc * 4, c0 = tr * 4;
  const int nbase = tile * TN;
  const float* xb = x + (size_t)b * CC * NN;
  const float* Mb = M + ((size_t)b << 14);

  // load X tile
  {
    const int g = t & 7, r0 = t >> 3;
#pragma unroll
    for (int k = 0; k < 4; ++k) {
      const int r = r0 + 32 * k;
      *(float4*)&Xs[r][g * 4] =
          *(const float4*)&xb[(size_t)r * NN + nbase + g * 4];
    }
  }
  __syncthreads();

  // Q projection (relu, bias) -> Qs
  {
    float aQ[4][4];
#pragma unroll
    for (int a = 0; a < 4; ++a)
#pragma unroll
      for (int j = 0; j < 4; ++j) aQ[a][j] = 0.f;

#pragma unroll 2
    for (int ci = 0; ci < CC; ci += 4) {
      const float4 x0 = *(const float4*)&Xs[ci + 0][n0];
      const float4 x1 = *(const float4*)&Xs[ci + 1][n0];
      const float4 x2 = *(const float4*)&Xs[ci + 2][n0];
      const float4 x3 = *(const float4*)&Xs[ci + 3][n0];
#pragma unroll
      for (int cc = 0; cc < 4; ++cc) {
        const float4 wq4 = *(const float4*)&Wq[(c0 + cc) * CC + ci];
        float* aQ_ = aQ[cc];
        RANK1(aQ_, wq4.x, x0); RANK1(aQ_, wq4.y, x1);
        RANK1(aQ_, wq4.z, x2); RANK1(aQ_, wq4.w, x3);
      }
    }
#pragma unroll
    for (int cc = 0; cc < 4; ++cc) {
      const float bb = bq[c0 + cc];
      float4 qo;
      qo.x = fmaxf(aQ[cc][0] + bb, 0.f);
      qo.y = fmaxf(aQ[cc][1] + bb, 0.f);
      qo.z = fmaxf(aQ[cc][2] + bb, 0.f);
      qo.w = fmaxf(aQ[cc][3] + bb, 0.f);
      *(float4*)&Qs[c0 + cc][n0] = qo;
    }
  }
  __syncthreads();

  // out tile = M @ Qs + br
  {
    float aO[4][4];
#pragma unroll
    for (int a = 0; a < 4; ++a)
#pragma unroll
      for (int j = 0; j < 4; ++j) aO[a][j] = 0.f;

#pragma unroll 2
    for (int c = 0; c < CC; c += 4) {
      const float4 q0 = *(const float4*)&Qs[c + 0][n0];
      const float4 q1 = *(const float4*)&Qs[c + 1][n0];
      const float4 q2 = *(const float4*)&Qs[c + 2][n0];
      const float4 q3 = *(const float4*)&Qs[c + 3][n0];
#pragma unroll
      for (int oo = 0; oo < 4; ++oo) {
        const float4 mw4 = *(const float4*)&Mb[(c0 + oo) * CC + c];
        float* aO_ = aO[oo];
        RANK1(aO_, mw4.x, q0); RANK1(aO_, mw4.y, q1);
        RANK1(aO_, mw4.z, q2); RANK1(aO_, mw4.w, q3);
      }
    }
#pragma unroll
    for (int oo = 0; oo < 4; ++oo) {
      const float bb = br[c0 + oo];
      float4 vo;
      vo.x = aO[oo][0] + bb;
      vo.y = aO[oo][1] + bb;
      vo.z = aO[oo][2] + bb;
      vo.w = aO[oo][3] + bb;
      *(float4*)&out[((size_t)b * CC + (c0 + oo)) * NN + nbase + n0] = vo;
    }
  }
}

// ---------------------------------------------------------------------------
extern "C" void kernel_launch(void* const* d_in, const int* in_sizes, int n_in,
                              void* d_out, int out_size, void* d_ws, size_t ws_size,
                              hipStream_t stream)
{
  const float* x  = (const float*)d_in[0];
  const float* Wk = (const float*)d_in[1];
  const float* bk = (const float*)d_in[2];
  const float* Wq = (const float*)d_in[3];
  const float* bq = (const float*)d_in[4];
  const float* Wv = (const float*)d_in[5];
  const float* bv = (const float*)d_in[6];
  const float* Wr = (const float*)d_in[7];
  const float* br = (const float*)d_in[8];
  // d_in[9] = head_count (constant 8, baked into kernels)
  float* out = (float*)d_out;

  float* ctx = (float*)d_ws;                                // BB*2048 floats = 32 KB
  float* M   = (float*)d_ws + (size_t)BB * HEADS * HD * HD; // BB*16384 floats = 256 KB

  (void)hipMemsetAsync(ctx, 0, (size_t)BB * HEADS * HD * HD * sizeof(float), stream);
  k1_context<<<dim3(K1_GRIDX, BB), TPB, 0, stream>>>(x, Wk, bk, Wv, bv, ctx);
  k2_fold<<<dim3(BB, 2), TPB, 0, stream>>>(Wr, ctx, M);
  k3_out<<<dim3(NTILES, BB), TPB, 0, stream>>>(x, Wq, bq, M, br, out);
}